// Round 5
// baseline (1958.995 us; speedup 1.0000x reference)
//
#include <hip/hip_runtime.h>
#include <cstdint>
#include <cmath>

// ============================================================================
// RBM_BB block Gibbs, bit-exact (R3 stripe-probe verified recipe = stripe s0):
//   keys   : partitionable threefry; fold-like split key_i = threefry(parent,0,i)
//   bits   : w0 ^ w1 of threefry(key, 0, flat_index); u = (bits>>9|1.0f)-1
//   sample : u < p
//   sigmoid: 1/(1+cephes_expf(-pre)), noFMA Horner, trailing max(res,x)
//   dot    : f32 sequential ascending-k, folded at kc=320 panel boundaries
// KERNEL IS R3'S VERBATIM (BK=32; the BK=64 variant had a staging bug:
// only 1024 of 2048 float4 slots loaded -> rows 64-127 stale. DO NOT revert
// to BK=64 without fixing staging to r<8.)
// ============================================================================

#define TF_ROT(x, r) (((x) << (r)) | ((x) >> (32 - (r))))

__host__ __device__ __forceinline__ void threefry2x32(
    uint32_t k0, uint32_t k1, uint32_t x0, uint32_t x1,
    uint32_t &o0, uint32_t &o1) {
  const uint32_t ks2 = k0 ^ k1 ^ 0x1BD11BDAu;
  x0 += k0; x1 += k1;
#define TF_R(r) { x0 += x1; x1 = TF_ROT(x1, r); x1 ^= x0; }
  TF_R(13) TF_R(15) TF_R(26) TF_R(6)
  x0 += k1; x1 += ks2 + 1u;
  TF_R(17) TF_R(29) TF_R(16) TF_R(24)
  x0 += ks2; x1 += k0 + 2u;
  TF_R(13) TF_R(15) TF_R(26) TF_R(6)
  x0 += k0; x1 += k1 + 3u;
  TF_R(17) TF_R(29) TF_R(16) TF_R(24)
  x0 += k1; x1 += ks2 + 4u;
  TF_R(13) TF_R(15) TF_R(26) TF_R(6)
  x0 += ks2; x1 += k0 + 5u;
#undef TF_R
  o0 = x0; o1 = x1;
}

// Cephes expf, noFMA (verified in-chain by R3 stripe 0).
__device__ __forceinline__ float cephes_expf(float xin) {
  float xc = fminf(xin, 88.3762626647950f);
  xc = fmaxf(xc, -88.3762626647949f);
  float fx = floorf(xc * 1.44269504088896341f + 0.5f);
  float tmp = 0.693359375f * fx;
  float z2  = -2.12194440e-4f * fx;
  float x = xc - tmp;
  x = x - z2;
  float z = x * x;
  float y = 1.9875691500E-4f * x + 1.3981999507E-3f;
  y = y * x + 8.3334519073E-3f;
  y = y * x + 4.1665795894E-2f;
  y = y * x + 1.6666665459E-1f;
  y = y * x + 5.0000001201E-1f;
  y = y * z + x;
  y = 1.0f + y;
  int n = (int)fx;
  float p2n = __uint_as_float((uint32_t)(n + 127) << 23);
  return fmaxf(y * p2n, xin);
}

// ----------------------------------------------------------------------------
// GEMM (128x128 tile, BK=32 — R3-verified) + fused Bernoulli sampling.
// ----------------------------------------------------------------------------
__global__ __launch_bounds__(256) void gemm_bt_sample(
    const float* __restrict__ A,    // [M, K] row-major
    const float* __restrict__ Bt,   // [N_total, K] row-major
    const float* __restrict__ bias, // [N_total]
    float* __restrict__ out,        // [M, N_total] binary f32
    int K, int N_total, int tiles_per_panel,
    uint32_t k0, uint32_t k1)
{
  __shared__ float As[128 * 32];
  __shared__ float Bs[128 * 32];
  const int t  = threadIdx.x;
  const int tx = t & 15;
  const int ty = t >> 4;
  const int bm = blockIdx.x;
  const int j0 = blockIdx.y << 7;

  float cur[8][8], tot[8][8];
#pragma unroll
  for (int i = 0; i < 8; ++i)
#pragma unroll
    for (int j = 0; j < 8; ++j) { cur[i][j] = 0.0f; tot[i][j] = 0.0f; }

  const long arow = (long)bm * 128 * K;
  const int ntiles = K >> 5;

  for (int tki = 0; tki < ntiles; ++tki) {
    const int kc = tki << 5;
#pragma unroll
    for (int r = 0; r < 4; ++r) {
      int q = t + 256 * r;          // 1024 float4 slots = full 128x32 tile
      int m = q >> 3;
      int c = q & 7;
      float4 val = *(const float4*)(A + arow + (long)m * K + kc + 4 * c);
      *(float4*)(As + m * 32 + ((c ^ (m & 7)) << 2)) = val;
    }
#pragma unroll
    for (int r = 0; r < 4; ++r) {
      int q = t + 256 * r;
      int n = q >> 3;
      int c = q & 7;
      float4 val = *(const float4*)(Bt + (long)(j0 + n) * K + kc + 4 * c);
      *(float4*)(Bs + n * 32 + ((c ^ (n & 7)) << 2)) = val;
    }
    __syncthreads();

#pragma unroll
    for (int c = 0; c < 8; ++c) {
      float4 av[8], bv[8];
#pragma unroll
      for (int i = 0; i < 8; ++i) {
        int m = ty + 16 * i;
        av[i] = *(const float4*)(As + m * 32 + ((c ^ (m & 7)) << 2));
      }
#pragma unroll
      for (int j = 0; j < 8; ++j) {
        int n = tx + 16 * j;
        bv[j] = *(const float4*)(Bs + n * 32 + ((c ^ (n & 7)) << 2));
      }
#pragma unroll
      for (int i = 0; i < 8; ++i)
#pragma unroll
        for (int j = 0; j < 8; ++j) {
          cur[i][j] = __fmaf_rn(av[i].x, bv[j].x, cur[i][j]);
          cur[i][j] = __fmaf_rn(av[i].y, bv[j].y, cur[i][j]);
          cur[i][j] = __fmaf_rn(av[i].z, bv[j].z, cur[i][j]);
          cur[i][j] = __fmaf_rn(av[i].w, bv[j].w, cur[i][j]);
        }
    }
    __syncthreads();

    if (((tki + 1) % tiles_per_panel == 0) || (tki == ntiles - 1)) {
#pragma unroll
      for (int i = 0; i < 8; ++i)
#pragma unroll
        for (int j = 0; j < 8; ++j) { tot[i][j] += cur[i][j]; cur[i][j] = 0.0f; }
    }
  }

#pragma unroll
  for (int i = 0; i < 8; ++i) {
    const int m = ty + 16 * i;
    const long b = (long)bm * 128 + m;
#pragma unroll
    for (int j = 0; j < 8; ++j) {
      const int n  = tx + 16 * j;
      const int ng = j0 + n;
      float pre = tot[i][j] + bias[ng];
      float p   = 1.0f / (1.0f + cephes_expf(-pre));
      uint32_t flat = (uint32_t)(b * N_total + ng);
      uint32_t w0, w1;
      threefry2x32(k0, k1, 0u, flat, w0, w1);
      uint32_t bits = w0 ^ w1;
      float u = __uint_as_float((bits >> 9) | 0x3f800000u) - 1.0f;
      out[(long)b * N_total + ng] = (u < p) ? 1.0f : 0.0f;
    }
  }
}

__global__ void transpose_W(const float* __restrict__ W, float* __restrict__ Wt) {
  __shared__ float tile[32][33];
  int bx = blockIdx.x, by = blockIdx.y;
  int x = threadIdx.x, y = threadIdx.y;
  tile[y][x] = W[(by * 32 + y) * 1024 + bx * 32 + x];
  __syncthreads();
  Wt[(bx * 32 + y) * 128 + by * 32 + x] = tile[x][y];
}

extern "C" void kernel_launch(void* const* d_in, const int* in_sizes, int n_in,
                              void* d_out, int out_size, void* d_ws, size_t ws_size,
                              hipStream_t stream) {
  const float* v0 = (const float*)d_in[0];   // [B,1024]
  const float* W  = (const float*)d_in[1];   // [128,1024]
  const float* bb = (const float*)d_in[2];   // [1024]
  const float* cb = (const float*)d_in[3];   // [128]
  const int B = in_sizes[0] / 1024;          // 32768

  float* out    = (float*)d_out;
  float* out_v  = out;                        // v_given_h   [B,1024]
  float* out_h1 = out + (size_t)B * 1024;     // h_given_v   [B,128]
  float* out_h2 = out_h1 + (size_t)B * 128;   // h_given_v_0 [B,128]

  float* Wt   = (float*)d_ws;                 // [1024,128]
  float* h_ws = Wt + 1024 * 128;              // [B,128]

  // partitionable keys: seed 42, fold-like split
  uint32_t kt[5][2], kv[5][2], kh[5][2];
  for (uint32_t i = 0; i < 5; ++i) threefry2x32(0u, 42u, 0u, i, kt[i][0], kt[i][1]);
  for (int t = 1; t <= 4; ++t) {
    threefry2x32(kt[t][0], kt[t][1], 0u, 0u, kv[t][0], kv[t][1]);
    threefry2x32(kt[t][0], kt[t][1], 0u, 1u, kh[t][0], kh[t][1]);
  }

  transpose_W<<<dim3(32, 4), dim3(32, 32), 0, stream>>>(W, Wt);

  const int MB = B / 128;        // 256
  const int TILES_PANEL = 10;    // 10 x 32 = kc=320 (K=128: single panel)

  // h0 = bernoulli(kt[0], sigmoid(W v0 + c))
  gemm_bt_sample<<<dim3(MB, 1), 256, 0, stream>>>(
      v0, W, cb, out_h2, 1024, 128, TILES_PANEL, kt[0][0], kt[0][1]);

  const float* h = out_h2;
  for (int t = 1; t <= 4; ++t) {
    // v_t = bernoulli(kv[t], sigmoid(W^T h + b))
    gemm_bt_sample<<<dim3(MB, 8), 256, 0, stream>>>(
        h, Wt, bb, out_v, 128, 1024, TILES_PANEL, kv[t][0], kv[t][1]);
    // h_t = bernoulli(kh[t], sigmoid(W v_t + c))
    float* hdst = (t == 4) ? out_h1 : h_ws;
    gemm_bt_sample<<<dim3(MB, 1), 256, 0, stream>>>(
        out_v, W, cb, hdst, 1024, 128, TILES_PANEL, kh[t][0], kh[t][1]);
    h = hdst;
  }
}

// Round 6
// 1602.354 us; speedup vs baseline: 1.2226x; 1.2226x over previous
//
#include <hip/hip_runtime.h>
#include <cstdint>

// ============================================================================
// RBM_BB block Gibbs, bit-exact (recipe frozen, R3/R5-verified):
//   keys   : partitionable threefry; fold-like split key_i = threefry(parent,0,i)
//   bits   : w0 ^ w1 of threefry(key, 0, flat_index); u = (bits>>9|1.0f)-1
//   sample : u < p
//   sigmoid: 1/(1+cephes_expf(-pre)), noFMA Horner, trailing max(res,x)
//   dot    : f32 sequential ascending-k, folded at kc=320 panel boundaries
// R6 perf: M64 tiles (half the acc VGPRs), SINGLE_PANEL template variant
// (no tot[] for K<=320 paths), split-K h-GEMM at panel boundaries (exact
// same fold sequence) with ws_size-checked fallback.
// ============================================================================

#define TF_ROT(x, r) (((x) << (r)) | ((x) >> (32 - (r))))

__host__ __device__ __forceinline__ void threefry2x32(
    uint32_t k0, uint32_t k1, uint32_t x0, uint32_t x1,
    uint32_t &o0, uint32_t &o1) {
  const uint32_t ks2 = k0 ^ k1 ^ 0x1BD11BDAu;
  x0 += k0; x1 += k1;
#define TF_R(r) { x0 += x1; x1 = TF_ROT(x1, r); x1 ^= x0; }
  TF_R(13) TF_R(15) TF_R(26) TF_R(6)
  x0 += k1; x1 += ks2 + 1u;
  TF_R(17) TF_R(29) TF_R(16) TF_R(24)
  x0 += ks2; x1 += k0 + 2u;
  TF_R(13) TF_R(15) TF_R(26) TF_R(6)
  x0 += k0; x1 += k1 + 3u;
  TF_R(17) TF_R(29) TF_R(16) TF_R(24)
  x0 += k1; x1 += ks2 + 4u;
  TF_R(13) TF_R(15) TF_R(26) TF_R(6)
  x0 += ks2; x1 += k0 + 5u;
#undef TF_R
  o0 = x0; o1 = x1;
}

// Cephes expf, noFMA (verified in-chain by R3 stripe 0 / R5).
__device__ __forceinline__ float cephes_expf(float xin) {
  float xc = fminf(xin, 88.3762626647950f);
  xc = fmaxf(xc, -88.3762626647949f);
  float fx = floorf(xc * 1.44269504088896341f + 0.5f);
  float tmp = 0.693359375f * fx;
  float z2  = -2.12194440e-4f * fx;
  float x = xc - tmp;
  x = x - z2;
  float z = x * x;
  float y = 1.9875691500E-4f * x + 1.3981999507E-3f;
  y = y * x + 8.3334519073E-3f;
  y = y * x + 4.1665795894E-2f;
  y = y * x + 1.6666665459E-1f;
  y = y * x + 5.0000001201E-1f;
  y = y * z + x;
  y = 1.0f + y;
  int n = (int)fx;
  float p2n = __uint_as_float((uint32_t)(n + 127) << 23);
  return fmaxf(y * p2n, xin);
}

__device__ __forceinline__ void sample_store(
    float tot, const float* bias, float* out,
    long b, int ng, int N_total, uint32_t k0, uint32_t k1) {
  float pre = tot + bias[ng];
  float p   = 1.0f / (1.0f + cephes_expf(-pre));
  uint32_t flat = (uint32_t)(b * N_total + ng);
  uint32_t w0, w1;
  threefry2x32(k0, k1, 0u, flat, w0, w1);
  uint32_t bits = w0 ^ w1;
  float u = __uint_as_float((bits >> 9) | 0x3f800000u) - 1.0f;
  out[(long)b * N_total + ng] = (u < p) ? 1.0f : 0.0f;
}

// ----------------------------------------------------------------------------
// GEMM, 64x128 tile, BK=32, 4x8 per thread.
// SAMPLE=1: full K, fused sigmoid+threefry epilogue.
// SAMPLE=0: split-K partial; blockIdx.z selects panel [z*320, min(K,z*320+320));
//           raw f32 partial written to out + z*Mtot*128.
// SINGLE_PANEL=1: no tot[] array (K-range <= one Eigen panel). Exactness:
//   single-panel total == 0 + P == P bitwise; multi-panel fold identical to R5.
// ----------------------------------------------------------------------------
template <bool SAMPLE, bool SINGLE_PANEL>
__global__ __launch_bounds__(256) void gemm_tile(
    const float* __restrict__ A,     // [Mtot, ldA] row-major
    const float* __restrict__ Bt,    // [N_total, ldA] row-major
    const float* __restrict__ bias,  // [N_total] (SAMPLE only)
    float* __restrict__ out,
    int ldA, int N_total, int K, int tiles_per_panel, int Mtot,
    uint32_t k0, uint32_t k1)
{
  __shared__ float As[64 * 32];
  __shared__ float Bs[128 * 32];
  const int t  = threadIdx.x;
  const int tx = t & 15;
  const int ty = t >> 4;
  const int bm = blockIdx.x;
  const int j0 = blockIdx.y << 7;

  int kb, ke;
  float* outp = out;
  if (SAMPLE) { kb = 0; ke = K; }
  else {
    const int z = blockIdx.z;
    kb = z * 320;
    ke = min(K, kb + 320);
    outp = out + (size_t)z * Mtot * 128;
  }

  float cur[4][8];
  float tot[4][8];
#pragma unroll
  for (int i = 0; i < 4; ++i)
#pragma unroll
    for (int j = 0; j < 8; ++j) { cur[i][j] = 0.0f; if (!SINGLE_PANEL) tot[i][j] = 0.0f; }

  const long arow = (long)bm * 64 * ldA;
  const int t0 = kb >> 5, t1 = ke >> 5;

  for (int tki = t0; tki < t1; ++tki) {
    const int kc = tki << 5;
    // stage A tile 64x32 = 512 float4 slots (2 per thread) — FULL tile
#pragma unroll
    for (int r = 0; r < 2; ++r) {
      int q = t + 256 * r;
      int m = q >> 3;
      int c = q & 7;
      float4 val = *(const float4*)(A + arow + (long)m * ldA + kc + 4 * c);
      *(float4*)(As + m * 32 + ((c ^ (m & 7)) << 2)) = val;
    }
    // stage B tile 128x32 = 1024 float4 slots (4 per thread) — FULL tile
#pragma unroll
    for (int r = 0; r < 4; ++r) {
      int q = t + 256 * r;
      int n = q >> 3;
      int c = q & 7;
      float4 val = *(const float4*)(Bt + (long)(j0 + n) * ldA + kc + 4 * c);
      *(float4*)(Bs + n * 32 + ((c ^ (n & 7)) << 2)) = val;
    }
    __syncthreads();

#pragma unroll
    for (int c = 0; c < 8; ++c) {
      float4 av[4], bv[8];
#pragma unroll
      for (int i = 0; i < 4; ++i) {
        int m = ty + 16 * i;
        av[i] = *(const float4*)(As + m * 32 + ((c ^ (m & 7)) << 2));
      }
#pragma unroll
      for (int j = 0; j < 8; ++j) {
        int n = tx + 16 * j;
        bv[j] = *(const float4*)(Bs + n * 32 + ((c ^ (n & 7)) << 2));
      }
#pragma unroll
      for (int i = 0; i < 4; ++i)
#pragma unroll
        for (int j = 0; j < 8; ++j) {
          cur[i][j] = __fmaf_rn(av[i].x, bv[j].x, cur[i][j]);
          cur[i][j] = __fmaf_rn(av[i].y, bv[j].y, cur[i][j]);
          cur[i][j] = __fmaf_rn(av[i].z, bv[j].z, cur[i][j]);
          cur[i][j] = __fmaf_rn(av[i].w, bv[j].w, cur[i][j]);
        }
    }
    __syncthreads();

    if (!SINGLE_PANEL) {
      if (((tki - t0 + 1) % tiles_per_panel == 0) || (tki == t1 - 1)) {
#pragma unroll
        for (int i = 0; i < 4; ++i)
#pragma unroll
          for (int j = 0; j < 8; ++j) { tot[i][j] += cur[i][j]; cur[i][j] = 0.0f; }
      }
    }
  }

#pragma unroll
  for (int i = 0; i < 4; ++i) {
    const int m = ty + 16 * i;
    const long b = (long)bm * 64 + m;
#pragma unroll
    for (int j = 0; j < 8; ++j) {
      const int n  = tx + 16 * j;
      const int ng = j0 + n;
      const float v = SINGLE_PANEL ? cur[i][j] : tot[i][j];
      if (SAMPLE) {
        sample_store(v, bias, outp, b, ng, N_total, k0, k1);
      } else {
        outp[b * 128 + ng] = v;   // raw panel partial (j0==0, N_total==128)
      }
    }
  }
}

// Fold 4 panel partials in exact order, then bias+sigmoid+sample.
__global__ __launch_bounds__(256) void combine_sample(
    const float* __restrict__ partials,  // [4][Mtot*128]
    const float* __restrict__ bias,      // [128]
    float* __restrict__ out,             // [Mtot*128] binary f32
    int Mtot, uint32_t k0, uint32_t k1)
{
  const long idx = (long)blockIdx.x * 256 + threadIdx.x;
  const long S = (long)Mtot * 128;
  float p0 = partials[idx];
  float p1 = partials[S + idx];
  float p2 = partials[2 * S + idx];
  float p3 = partials[3 * S + idx];
  float tot = ((p0 + p1) + p2) + p3;          // Eigen fold order, exact
  float pre = tot + bias[(int)(idx & 127)];
  float p   = 1.0f / (1.0f + cephes_expf(-pre));
  uint32_t w0, w1;
  threefry2x32(k0, k1, 0u, (uint32_t)idx, w0, w1);
  uint32_t bits = w0 ^ w1;
  float u = __uint_as_float((bits >> 9) | 0x3f800000u) - 1.0f;
  out[idx] = (u < p) ? 1.0f : 0.0f;
}

__global__ void transpose_W(const float* __restrict__ W, float* __restrict__ Wt) {
  __shared__ float tile[32][33];
  int bx = blockIdx.x, by = blockIdx.y;
  int x = threadIdx.x, y = threadIdx.y;
  tile[y][x] = W[(by * 32 + y) * 1024 + bx * 32 + x];
  __syncthreads();
  Wt[(bx * 32 + y) * 128 + by * 32 + x] = tile[x][y];
}

extern "C" void kernel_launch(void* const* d_in, const int* in_sizes, int n_in,
                              void* d_out, int out_size, void* d_ws, size_t ws_size,
                              hipStream_t stream) {
  const float* v0 = (const float*)d_in[0];   // [B,1024]
  const float* W  = (const float*)d_in[1];   // [128,1024]
  const float* bb = (const float*)d_in[2];   // [1024]
  const float* cb = (const float*)d_in[3];   // [128]
  const int B = in_sizes[0] / 1024;          // 32768

  float* out    = (float*)d_out;
  float* out_v  = out;                        // v_given_h   [B,1024]
  float* out_h1 = out + (size_t)B * 1024;     // h_given_v   [B,128]
  float* out_h2 = out_h1 + (size_t)B * 128;   // h_given_v_0 [B,128]

  float* Wt       = (float*)d_ws;                       // [1024,128]
  float* h_ws     = Wt + 1024 * 128;                    // [B,128]
  float* partials = h_ws + (size_t)B * 128;             // [4][B,128]
  const size_t need = (size_t)(1024 * 128 + (size_t)B * 128 * 5) * 4;
  const bool use_split = ws_size >= need;

  // partitionable keys: seed 42, fold-like split
  uint32_t kt[5][2], kv[5][2], kh[5][2];
  for (uint32_t i = 0; i < 5; ++i) threefry2x32(0u, 42u, 0u, i, kt[i][0], kt[i][1]);
  for (int t = 1; t <= 4; ++t) {
    threefry2x32(kt[t][0], kt[t][1], 0u, 0u, kv[t][0], kv[t][1]);
    threefry2x32(kt[t][0], kt[t][1], 0u, 1u, kh[t][0], kh[t][1]);
  }

  transpose_W<<<dim3(32, 4), dim3(32, 32), 0, stream>>>(W, Wt);

  const int MB = B / 64;     // 512 row-blocks

  // h-step: hdst = bernoulli(key, sigmoid(W vin + c))
  auto h_step = [&](const float* vin, float* hdst, uint32_t hk0, uint32_t hk1) {
    if (use_split) {
      gemm_tile<false, true><<<dim3(MB, 1, 4), 256, 0, stream>>>(
          vin, W, nullptr, partials, 1024, 128, 1024, 1000, B, 0u, 0u);
      combine_sample<<<dim3(B * 128 / 256), 256, 0, stream>>>(
          partials, cb, hdst, B, hk0, hk1);
    } else {
      gemm_tile<true, false><<<dim3(MB, 1, 1), 256, 0, stream>>>(
          vin, W, cb, hdst, 1024, 128, 1024, 10, B, hk0, hk1);
    }
  };

  // h0 = bernoulli(kt[0], sigmoid(W v0 + c))
  h_step(v0, out_h2, kt[0][0], kt[0][1]);

  const float* h = out_h2;
  for (int t = 1; t <= 4; ++t) {
    // v_t = bernoulli(kv[t], sigmoid(W^T h + b)) — K=128, single panel
    gemm_tile<true, true><<<dim3(MB, 8, 1), 256, 0, stream>>>(
        h, Wt, bb, out_v, 128, 1024, 128, 10, B, kv[t][0], kv[t][1]);
    // h_t = bernoulli(kh[t], sigmoid(W v_t + c))
    float* hdst = (t == 4) ? out_h1 : h_ws;
    h_step(out_v, hdst, kh[t][0], kh[t][1]);
    h = hdst;
  }
}